// Round 1
// baseline (1494.560 us; speedup 1.0000x reference)
//
#include <hip/hip_runtime.h>
#include <math.h>

// Problem constants
// B=16, L=2048, D=128, H=4, HD=32, FF=256, MD=32, C1=128, C2=256, K=5, NC=2

// ---------------------------------------------------------------- embed
__global__ __launch_bounds__(256) void k_embed(const int* __restrict__ X, const float* __restrict__ sa,
                        const int* __restrict__ ptm, const float* __restrict__ emb,
                        const float* __restrict__ pemb, float* __restrict__ x0) {
    int idx = blockIdx.x * 256 + threadIdx.x;   // B*L*128 = 4194304
    int row = idx >> 7, e = idx & 127;
    float v;
    if (e < 120) v = emb[X[row] * 120 + e] * sa[row];
    else         v = pemb[ptm[row] * 8 + (e - 120)];
    x0[idx] = v;
}

// ---------------------------------------------------------------- QKV GEMM
// qkv = x0 @ in_proj_w.T + b ; scatter into Q/K/V [B*H][L][32]
__global__ __launch_bounds__(256) void k_qkv(const float* __restrict__ x0, const float* __restrict__ W,
                      const float* __restrict__ bias, float* __restrict__ Qd,
                      float* __restrict__ Kd, float* __restrict__ Vd) {
    __shared__ float Ast[32][68];
    __shared__ float Bst[32][68];
    int m0 = blockIdx.y * 64, n0 = blockIdx.x * 64;
    int t = threadIdx.x, tx = t & 15, ty = t >> 4;
    float acc[4][4] = {};
    for (int kk = 0; kk < 128; kk += 32) {
        __syncthreads();
#pragma unroll
        for (int i = 0; i < 2; i++) {
            int idx = t + i * 256;
            int row = idx >> 3, c4 = (idx & 7) * 4;
            float4 a = *(const float4*)&x0[(m0 + row) * 128 + kk + c4];
            Ast[c4 + 0][row] = a.x; Ast[c4 + 1][row] = a.y;
            Ast[c4 + 2][row] = a.z; Ast[c4 + 3][row] = a.w;
            float4 b = *(const float4*)&W[(n0 + row) * 128 + kk + c4];
            Bst[c4 + 0][row] = b.x; Bst[c4 + 1][row] = b.y;
            Bst[c4 + 2][row] = b.z; Bst[c4 + 3][row] = b.w;
        }
        __syncthreads();
#pragma unroll
        for (int k2 = 0; k2 < 32; k2++) {
            float4 a4 = *(const float4*)&Ast[k2][ty * 4];
            float4 b4 = *(const float4*)&Bst[k2][tx * 4];
            acc[0][0] += a4.x * b4.x; acc[0][1] += a4.x * b4.y; acc[0][2] += a4.x * b4.z; acc[0][3] += a4.x * b4.w;
            acc[1][0] += a4.y * b4.x; acc[1][1] += a4.y * b4.y; acc[1][2] += a4.y * b4.z; acc[1][3] += a4.y * b4.w;
            acc[2][0] += a4.z * b4.x; acc[2][1] += a4.z * b4.y; acc[2][2] += a4.z * b4.z; acc[2][3] += a4.z * b4.w;
            acc[3][0] += a4.w * b4.x; acc[3][1] += a4.w * b4.y; acc[3][2] += a4.w * b4.z; acc[3][3] += a4.w * b4.w;
        }
    }
    int n = n0 + tx * 4;              // 4 consecutive cols, never straddles 32-boundary
    float4 bv = *(const float4*)&bias[n];
    int which = n >> 7, h = (n & 127) >> 5, hd = n & 31;
    float* dst = (which == 0) ? Qd : ((which == 1) ? Kd : Vd);
#pragma unroll
    for (int ii = 0; ii < 4; ii++) {
        int m = m0 + ty * 4 + ii;
        int bb = m >> 11, l = m & 2047;
        float4 o;
        o.x = acc[ii][0] + bv.x; o.y = acc[ii][1] + bv.y;
        o.z = acc[ii][2] + bv.z; o.w = acc[ii][3] + bv.w;
        *(float4*)&dst[(((size_t)(bb * 4 + h) * 2048) + l) * 32 + hd] = o;
    }
}

// ---------------------------------------------------------------- flash attention
__global__ __launch_bounds__(256) void k_attn(const float* __restrict__ Q, const float* __restrict__ Kv,
                       const float* __restrict__ V, const float* __restrict__ rpe,
                       float* __restrict__ AO) {
    __shared__ float Qs[64][36];
    __shared__ float Kts[32][68];
    __shared__ float Vs[64][32];
    __shared__ float Sm[64][68];
    __shared__ float sbias[68];
    int bh = blockIdx.y;          // b*4+h
    int h = bh & 3, bb = bh >> 2;
    int i0 = blockIdx.x * 64;
    int t = threadIdx.x, tx = t & 15, ty = t >> 4;
    const float* Qb = Q + (size_t)bh * 2048 * 32;
    const float* Kb = Kv + (size_t)bh * 2048 * 32;
    const float* Vb = V + (size_t)bh * 2048 * 32;
    if (t < 65) sbias[t] = rpe[t * 4 + h];
#pragma unroll
    for (int i = 0; i < 2; i++) {
        int idx = t + i * 256; int row = idx >> 3, c4 = (idx & 7) * 4;
        *(float4*)&Qs[row][c4] = *(const float4*)&Qb[(i0 + row) * 32 + c4];
    }
    float m_i[4], l_i[4], o0[4], o1[4];
#pragma unroll
    for (int r = 0; r < 4; r++) { m_i[r] = -1e30f; l_i[r] = 0.f; o0[r] = 0.f; o1[r] = 0.f; }
    const float scale = 0.17677669529663687f;   // 1/sqrt(32)

    for (int j0 = 0; j0 < 2048; j0 += 64) {
        __syncthreads();
#pragma unroll
        for (int i = 0; i < 2; i++) {
            int idx = t + i * 256; int row = idx >> 3, c4 = (idx & 7) * 4;
            float4 kq = *(const float4*)&Kb[(j0 + row) * 32 + c4];
            Kts[c4 + 0][row] = kq.x; Kts[c4 + 1][row] = kq.y;
            Kts[c4 + 2][row] = kq.z; Kts[c4 + 3][row] = kq.w;
            *(float4*)&Vs[row][c4] = *(const float4*)&Vb[(j0 + row) * 32 + c4];
        }
        __syncthreads();
        float s[4][4] = {};
#pragma unroll
        for (int hd0 = 0; hd0 < 32; hd0 += 4) {
            float4 qv[4], kv[4];
#pragma unroll
            for (int ii = 0; ii < 4; ii++) qv[ii] = *(const float4*)&Qs[ty * 4 + ii][hd0];
#pragma unroll
            for (int hq = 0; hq < 4; hq++) kv[hq] = *(const float4*)&Kts[hd0 + hq][tx * 4];
#pragma unroll
            for (int ii = 0; ii < 4; ii++) {
                s[ii][0] += qv[ii].x * kv[0].x + qv[ii].y * kv[1].x + qv[ii].z * kv[2].x + qv[ii].w * kv[3].x;
                s[ii][1] += qv[ii].x * kv[0].y + qv[ii].y * kv[1].y + qv[ii].z * kv[2].y + qv[ii].w * kv[3].y;
                s[ii][2] += qv[ii].x * kv[0].z + qv[ii].y * kv[1].z + qv[ii].z * kv[2].z + qv[ii].w * kv[3].z;
                s[ii][3] += qv[ii].x * kv[0].w + qv[ii].y * kv[1].w + qv[ii].z * kv[2].w + qv[ii].w * kv[3].w;
            }
        }
#pragma unroll
        for (int ii = 0; ii < 4; ii++) {
            int ig = i0 + ty * 4 + ii;
            float sv[4]; float tmax = -1e30f;
#pragma unroll
            for (int jj = 0; jj < 4; jj++) {
                int jg = j0 + tx * 4 + jj;
                int d = jg - ig; d = (d < -32) ? -32 : (d > 32 ? 32 : d);
                float val = s[ii][jj] * scale + sbias[d + 32];
                sv[jj] = val; tmax = fmaxf(tmax, val);
            }
#pragma unroll
            for (int off = 1; off < 16; off <<= 1) tmax = fmaxf(tmax, __shfl_xor(tmax, off));
            float mnew = fmaxf(m_i[ii], tmax);
            float alpha = __expf(m_i[ii] - mnew);
            float4 p4;
            p4.x = __expf(sv[0] - mnew); p4.y = __expf(sv[1] - mnew);
            p4.z = __expf(sv[2] - mnew); p4.w = __expf(sv[3] - mnew);
            float psum = p4.x + p4.y + p4.z + p4.w;
#pragma unroll
            for (int off = 1; off < 16; off <<= 1) psum += __shfl_xor(psum, off);
            l_i[ii] = l_i[ii] * alpha + psum;
            m_i[ii] = mnew;
            o0[ii] *= alpha; o1[ii] *= alpha;
            *(float4*)&Sm[ty * 4 + ii][tx * 4] = p4;
        }
        __syncthreads();
#pragma unroll
        for (int j4 = 0; j4 < 16; j4++) {
            float4 p4[4]; float2 v2[4];
#pragma unroll
            for (int r = 0; r < 4; r++) p4[r] = *(const float4*)&Sm[ty * 4 + r][j4 * 4];
#pragma unroll
            for (int jq = 0; jq < 4; jq++) v2[jq] = *(const float2*)&Vs[j4 * 4 + jq][tx * 2];
#pragma unroll
            for (int r = 0; r < 4; r++) {
                o0[r] += p4[r].x * v2[0].x + p4[r].y * v2[1].x + p4[r].z * v2[2].x + p4[r].w * v2[3].x;
                o1[r] += p4[r].x * v2[0].y + p4[r].y * v2[1].y + p4[r].z * v2[2].y + p4[r].w * v2[3].y;
            }
        }
    }
#pragma unroll
    for (int r = 0; r < 4; r++) {
        int l = i0 + ty * 4 + r;
        float inv = 1.0f / l_i[r];
        float2 o; o.x = o0[r] * inv; o.y = o1[r] * inv;
        *(float2*)&AO[((size_t)(bb * 2048 + l) * 128) + h * 32 + tx * 2] = o;
    }
}

// ---------------------------------------------------------------- out-proj + residual + LN1
__global__ __launch_bounds__(256) void k_outproj_ln(const float* __restrict__ AO, const float* __restrict__ W,
        const float* __restrict__ bias, const float* __restrict__ x0,
        const float* __restrict__ g, const float* __restrict__ be, float* __restrict__ x1) {
    __shared__ float AOs[8][132];
    __shared__ float parts[4][4][2];
    int r0 = blockIdx.x * 8;
    int t = threadIdx.x;
    { int row = t >> 5, c4 = (t & 31) * 4;
      *(float4*)&AOs[row][c4] = *(const float4*)&AO[(size_t)(r0 + row) * 128 + c4]; }
    __syncthreads();
    int rg = t >> 7, d = t & 127;
    float acc[4] = {0.f, 0.f, 0.f, 0.f};
    const float4* W4 = (const float4*)(W + d * 128);
#pragma unroll
    for (int k4 = 0; k4 < 32; k4++) {
        float4 w = W4[k4];
#pragma unroll
        for (int rr = 0; rr < 4; rr++) {
            float4 a = *(const float4*)&AOs[rg * 4 + rr][k4 * 4];
            acc[rr] += w.x * a.x + w.y * a.y + w.z * a.z + w.w * a.w;
        }
    }
    float bd = bias[d];
    float vals[4];
#pragma unroll
    for (int rr = 0; rr < 4; rr++) {
        int row = r0 + rg * 4 + rr;
        vals[rr] = acc[rr] + bd + x0[(size_t)row * 128 + d];
    }
    int wv = t >> 6, lane = t & 63;
    float ssum[4], ssq[4];
#pragma unroll
    for (int rr = 0; rr < 4; rr++) {
        float a = vals[rr], b2 = vals[rr] * vals[rr];
#pragma unroll
        for (int off = 1; off < 64; off <<= 1) { a += __shfl_xor(a, off); b2 += __shfl_xor(b2, off); }
        ssum[rr] = a; ssq[rr] = b2;
    }
    if (lane == 0)
#pragma unroll
        for (int rr = 0; rr < 4; rr++) { parts[wv][rr][0] = ssum[rr]; parts[wv][rr][1] = ssq[rr]; }
    __syncthreads();
    int wo = wv ^ 1;
#pragma unroll
    for (int rr = 0; rr < 4; rr++) {
        float ts = parts[wv][rr][0] + parts[wo][rr][0];
        float tq = parts[wv][rr][1] + parts[wo][rr][1];
        float mean = ts * (1.0f / 128.0f);
        float var = tq * (1.0f / 128.0f) - mean * mean;
        float rs = rsqrtf(var + 1e-5f);
        int row = r0 + rg * 4 + rr;
        x1[(size_t)row * 128 + d] = (vals[rr] - mean) * rs * g[d] + be[d];
    }
}

// ---------------------------------------------------------------- FFN + residual + LN2
__global__ __launch_bounds__(256) void k_ffn_ln(const float* __restrict__ x1, const float* __restrict__ W1,
        const float* __restrict__ b1, const float* __restrict__ W2, const float* __restrict__ b2,
        const float* __restrict__ g, const float* __restrict__ be, float* __restrict__ x2) {
    __shared__ float xs[8][132];
    __shared__ float hst[8][260];
    __shared__ float parts[4][4][2];
    int r0 = blockIdx.x * 8;
    int t = threadIdx.x;
    { int row = t >> 5, c4 = (t & 31) * 4;
      *(float4*)&xs[row][c4] = *(const float4*)&x1[(size_t)(r0 + row) * 128 + c4]; }
    __syncthreads();
    float hacc[8] = {};
    const float4* W14 = (const float4*)(W1 + t * 128);
#pragma unroll
    for (int k4 = 0; k4 < 32; k4++) {
        float4 w = W14[k4];
#pragma unroll
        for (int r = 0; r < 8; r++) {
            float4 a = *(const float4*)&xs[r][k4 * 4];
            hacc[r] += w.x * a.x + w.y * a.y + w.z * a.z + w.w * a.w;
        }
    }
    float bb1 = b1[t];
#pragma unroll
    for (int r = 0; r < 8; r++) hst[r][t] = fmaxf(hacc[r] + bb1, 0.f);
    __syncthreads();
    int rg = t >> 7, d = t & 127;
    float acc[4] = {0.f, 0.f, 0.f, 0.f};
    const float4* W24 = (const float4*)(W2 + d * 256);
#pragma unroll
    for (int j4 = 0; j4 < 64; j4++) {
        float4 w = W24[j4];
#pragma unroll
        for (int rr = 0; rr < 4; rr++) {
            float4 hv = *(const float4*)&hst[rg * 4 + rr][j4 * 4];
            acc[rr] += w.x * hv.x + w.y * hv.y + w.z * hv.z + w.w * hv.w;
        }
    }
    float bd = b2[d];
    float vals[4];
#pragma unroll
    for (int rr = 0; rr < 4; rr++) vals[rr] = acc[rr] + bd + xs[rg * 4 + rr][d];
    int wv = t >> 6, lane = t & 63;
    float ssum[4], ssq[4];
#pragma unroll
    for (int rr = 0; rr < 4; rr++) {
        float a = vals[rr], q = vals[rr] * vals[rr];
#pragma unroll
        for (int off = 1; off < 64; off <<= 1) { a += __shfl_xor(a, off); q += __shfl_xor(q, off); }
        ssum[rr] = a; ssq[rr] = q;
    }
    if (lane == 0)
#pragma unroll
        for (int rr = 0; rr < 4; rr++) { parts[wv][rr][0] = ssum[rr]; parts[wv][rr][1] = ssq[rr]; }
    __syncthreads();
    int wo = wv ^ 1;
#pragma unroll
    for (int rr = 0; rr < 4; rr++) {
        float ts = parts[wv][rr][0] + parts[wo][rr][0];
        float tq = parts[wv][rr][1] + parts[wo][rr][1];
        float mean = ts * (1.0f / 128.0f);
        float var = tq * (1.0f / 128.0f) - mean * mean;
        float rs = rsqrtf(var + 1e-5f);
        int row = r0 + rg * 4 + rr;
        x2[(size_t)row * 128 + d] = (vals[rr] - mean) * rs * g[d] + be[d];
    }
}

// ---------------------------------------------------------------- conv (Cin=128 fixed), in [b][Lin][128], wt [ci][k][Cout], out [b][Lout][Cout]
__global__ __launch_bounds__(256) void k_conv(const float* __restrict__ in, const float* __restrict__ wt,
        const float* __restrict__ bias, float* __restrict__ out,
        int Lin, int Lout, int Cout, int pad) {
    __shared__ float s_in[68][132];
    __shared__ float s_w[5120];
    int b = blockIdx.z, lt = blockIdx.y, ct = blockIdx.x;
    int lbase = lt * 64, co0 = ct * 64;
    int t = threadIdx.x, tx = t & 15, ty = t >> 4;
#pragma unroll
    for (int i = 0; i < 9; i++) {
        int idx = t + i * 256;             // 2176 float4s
        if (idx < 2176) {
            int row = idx >> 5, c4 = (idx & 31) * 4;
            int gl = lbase - pad + row;
            float4 v = {0.f, 0.f, 0.f, 0.f};
            if (gl >= 0 && gl < Lin) v = *(const float4*)&in[((size_t)b * Lin + gl) * 128 + c4];
            *(float4*)&s_in[row][c4] = v;
        }
    }
    float acc[4][4] = {};
    for (int ci0 = 0; ci0 < 128; ci0 += 16) {
        __syncthreads();
#pragma unroll
        for (int i = 0; i < 5; i++) {
            int f4i = t + i * 256;          // 1280 float4s
            int flat = f4i * 4;
            int ci = flat / 320, rem = flat % 320;
            int kq = rem >> 6, co = rem & 63;
            *(float4*)&s_w[flat] = *(const float4*)&wt[((size_t)(ci0 + ci) * 5 + kq) * Cout + co0 + co];
        }
        __syncthreads();
#pragma unroll
        for (int ci = 0; ci < 16; ci++) {
            float a8[8];
#pragma unroll
            for (int x = 0; x < 8; x++) a8[x] = s_in[ty * 4 + x][ci0 + ci];
#pragma unroll
            for (int kq = 0; kq < 5; kq++) {
                float4 w = *(const float4*)&s_w[(ci * 5 + kq) * 64 + tx * 4];
#pragma unroll
                for (int il = 0; il < 4; il++) {
                    float a = a8[il + kq];
                    acc[il][0] += a * w.x; acc[il][1] += a * w.y;
                    acc[il][2] += a * w.z; acc[il][3] += a * w.w;
                }
            }
        }
    }
    float4 bv = *(const float4*)&bias[co0 + tx * 4];
#pragma unroll
    for (int il = 0; il < 4; il++) {
        int l = lbase + ty * 4 + il;
        if (l < Lout) {
            float4 o;
            o.x = acc[il][0] + bv.x; o.y = acc[il][1] + bv.y;
            o.z = acc[il][2] + bv.z; o.w = acc[il][3] + bv.w;
            *(float4*)&out[((size_t)b * Lout + l) * Cout + co0 + tx * 4] = o;
        }
    }
}

// ---------------------------------------------------------------- BN stats (two-stage, deterministic)
template <int C>
__global__ __launch_bounds__(256) void k_bnstats(const float* __restrict__ in, int rows, float* __restrict__ part) {
    __shared__ float buf[256][2];
    constexpr int RPI = 256 / C;
    int t = threadIdx.x;
    int c = t % C, rsub = t / C;
    float s = 0.f, s2 = 0.f;
    for (int r = blockIdx.x * RPI + rsub; r < rows; r += 256 * RPI) {
        float v = in[(size_t)r * C + c];
        s += v; s2 += v * v;
    }
    if (RPI > 1) {
        buf[t][0] = s; buf[t][1] = s2;
        __syncthreads();
        if (t < C) {
            s = buf[t][0] + buf[t + C][0];
            s2 = buf[t][1] + buf[t + C][1];
            part[(blockIdx.x * C + t) * 2] = s;
            part[(blockIdx.x * C + t) * 2 + 1] = s2;
        }
    } else {
        part[(blockIdx.x * C + c) * 2] = s;
        part[(blockIdx.x * C + c) * 2 + 1] = s2;
    }
}

__global__ void k_bnfin(const float* __restrict__ part, const float* __restrict__ g,
                        const float* __restrict__ be, float N, int C, float* __restrict__ ss) {
    int c = threadIdx.x;
    if (c >= C) return;
    float s = 0.f, s2 = 0.f;
    for (int pb = 0; pb < 256; pb++) {
        s += part[(pb * C + c) * 2];
        s2 += part[(pb * C + c) * 2 + 1];
    }
    float mean = s / N, var = s2 / N - mean * mean;
    float sc = g[c] * rsqrtf(var + 1e-5f);
    ss[c] = sc;
    ss[C + c] = be[c] - mean * sc;
}

// ---------------------------------------------------------------- BN1 + relu + maxpool(2)
__global__ __launch_bounds__(256) void k_bnrelu_pool(const float* __restrict__ c1, const float* __restrict__ ss,
                                                     float* __restrict__ p1) {
    int idx = blockIdx.x * 256 + threadIdx.x;    // 16*1024*128
    int c = idx & 127;
    int lp = (idx >> 7) & 1023;
    int b = idx >> 17;
    float sc = ss[c], sh = ss[128 + c];
    float v0 = c1[((size_t)b * 2048 + 2 * lp) * 128 + c];
    float v1 = c1[((size_t)b * 2048 + 2 * lp + 1) * 128 + c];
    float r0 = fmaxf(sc * v0 + sh, 0.f), r1 = fmaxf(sc * v1 + sh, 0.f);
    p1[idx] = fmaxf(r0, r1);
}

// ---------------------------------------------------------------- BN2 + relu + partial global max
__global__ __launch_bounds__(256) void k_pmax(const float* __restrict__ c2, const float* __restrict__ ss,
                                              float* __restrict__ pmax) {
    int ch = blockIdx.x, b = blockIdx.y;
    int c = threadIdx.x;
    float sc = ss[c], sh = ss[256 + c];
    float m = -1e30f;
    int lend = ch * 128 + 128; if (lend > 1020) lend = 1020;
    for (int l = ch * 128; l < lend; l++) {
        float v = c2[((size_t)b * 1020 + l) * 256 + c];
        m = fmaxf(m, sc * v + sh);
    }
    m = fmaxf(m, 0.f);     // relu(max) == max(relu)
    pmax[(b * 8 + ch) * 256 + c] = m;
}

// ---------------------------------------------------------------- final max + FC
__global__ __launch_bounds__(256) void k_fc(const float* __restrict__ pmax, const float* __restrict__ fcw,
                                            const float* __restrict__ fcb, float* __restrict__ outp) {
    __shared__ float red0[256], red1[256];
    int b = blockIdx.x, c = threadIdx.x;
    float m = 0.f;
#pragma unroll
    for (int ch = 0; ch < 8; ch++) m = fmaxf(m, pmax[(b * 8 + ch) * 256 + c]);
    red0[c] = fcw[c] * m;
    red1[c] = fcw[256 + c] * m;
    __syncthreads();
    for (int s = 128; s > 0; s >>= 1) {
        if (c < s) { red0[c] += red0[c + s]; red1[c] += red1[c + s]; }
        __syncthreads();
    }
    if (c == 0) { outp[b * 2] = red0[0] + fcb[0]; outp[b * 2 + 1] = red1[0] + fcb[1]; }
}

// ---------------------------------------------------------------- conv weight transpose [co][ci][k] -> [ci][k][co]
__global__ __launch_bounds__(256) void k_transw(const float* __restrict__ w1, const float* __restrict__ w2,
                                                float* __restrict__ wt1, float* __restrict__ wt2) {
    int idx = blockIdx.x * 256 + threadIdx.x;
    if (idx < 128 * 5 * 128) {
        int ci = idx / 640, rem = idx % 640, kq = rem >> 7, co = rem & 127;
        wt1[idx] = w1[(co * 128 + ci) * 5 + kq];
    }
    if (idx < 128 * 5 * 256) {
        int ci = idx / 1280, rem = idx % 1280, kq = rem >> 8, co = rem & 255;
        wt2[idx] = w2[(co * 128 + ci) * 5 + kq];
    }
}

// ---------------------------------------------------------------- launch
extern "C" void kernel_launch(void* const* d_in, const int* in_sizes, int n_in,
                              void* d_out, int out_size, void* d_ws, size_t ws_size,
                              hipStream_t stream) {
    const int*   X    = (const int*)d_in[0];
    const float* sa   = (const float*)d_in[1];
    const int*   ptm  = (const int*)d_in[2];
    const float* emb  = (const float*)d_in[3];
    const float* pemb = (const float*)d_in[4];
    const float* rpe  = (const float*)d_in[5];
    const float* ipw  = (const float*)d_in[6];
    const float* ipb  = (const float*)d_in[7];
    const float* opw  = (const float*)d_in[8];
    const float* opb  = (const float*)d_in[9];
    const float* l1w  = (const float*)d_in[10];
    const float* l1b  = (const float*)d_in[11];
    const float* l2w  = (const float*)d_in[12];
    const float* l2b  = (const float*)d_in[13];
    const float* ln1g = (const float*)d_in[14];
    const float* ln1b = (const float*)d_in[15];
    const float* ln2g = (const float*)d_in[16];
    const float* ln2b = (const float*)d_in[17];
    const float* c1w  = (const float*)d_in[18];
    const float* c1b  = (const float*)d_in[19];
    const float* bn1g = (const float*)d_in[20];
    const float* bn1b = (const float*)d_in[21];
    const float* c2w  = (const float*)d_in[22];
    const float* c2b  = (const float*)d_in[23];
    const float* bn2g = (const float*)d_in[24];
    const float* bn2b = (const float*)d_in[25];
    const float* fcw  = (const float*)d_in[26];
    const float* fcb  = (const float*)d_in[27];

    float* ws = (float*)d_ws;
    const size_t S = 4194304;          // one [16,2048,128] slot
    float* x0  = ws;                   // slot0: x0, later c2
    float* Qd  = ws + S;               // slot1: Q, later x1
    float* Kd  = ws + 2 * S;           // slot2: K, later x2
    float* Vd  = ws + 3 * S;           // slot3: V, later c1
    float* AO  = ws + 4 * S;           // slot4: AO, later p1
    float* x1  = Qd;
    float* x2  = Kd;
    float* c1  = Vd;
    float* p1  = AO;
    float* c2  = x0;
    float* sm    = ws + 5 * S;
    float* wt1   = sm;                 // 81920
    float* wt2   = sm + 81920;         // 163840
    float* part1 = sm + 245760;        // 65536
    float* part2 = sm + 311296;        // 131072
    float* ss1   = sm + 442368;        // 256
    float* ss2   = sm + 442624;        // 512
    float* pmax  = sm + 443136;        // 32768

    k_transw<<<dim3(640), dim3(256), 0, stream>>>(c1w, c2w, wt1, wt2);
    k_embed<<<dim3(16384), dim3(256), 0, stream>>>(X, sa, ptm, emb, pemb, x0);
    k_qkv<<<dim3(6, 512), dim3(256), 0, stream>>>(x0, ipw, ipb, Qd, Kd, Vd);
    k_attn<<<dim3(32, 64), dim3(256), 0, stream>>>(Qd, Kd, Vd, rpe, AO);
    k_outproj_ln<<<dim3(4096), dim3(256), 0, stream>>>(AO, opw, opb, x0, ln1g, ln1b, x1);
    k_ffn_ln<<<dim3(4096), dim3(256), 0, stream>>>(x1, l1w, l1b, l2w, l2b, ln2g, ln2b, x2);
    k_conv<<<dim3(2, 32, 16), dim3(256), 0, stream>>>(x2, wt1, c1b, c1, 2048, 2048, 128, 2);
    k_bnstats<128><<<dim3(256), dim3(256), 0, stream>>>(c1, 32768, part1);
    k_bnfin<<<dim3(1), dim3(128), 0, stream>>>(part1, bn1g, bn1b, 32768.0f, 128, ss1);
    k_bnrelu_pool<<<dim3(8192), dim3(256), 0, stream>>>(c1, ss1, p1);
    k_conv<<<dim3(4, 16, 16), dim3(256), 0, stream>>>(p1, wt2, c2b, c2, 1024, 1020, 256, 0);
    k_bnstats<256><<<dim3(256), dim3(256), 0, stream>>>(c2, 16320, part2);
    k_bnfin<<<dim3(1), dim3(256), 0, stream>>>(part2, bn2g, bn2b, 16320.0f, 256, ss2);
    k_pmax<<<dim3(8, 16), dim3(256), 0, stream>>>(c2, ss2, pmax);
    k_fc<<<dim3(16), dim3(256), 0, stream>>>(pmax, fcw, fcb, (float*)d_out);
}

// Round 2
// 800.389 us; speedup vs baseline: 1.8673x; 1.8673x over previous
//
#include <hip/hip_runtime.h>
#include <math.h>

// Problem constants
// B=16, L=2048, D=128, H=4, HD=32, FF=256, MD=32, C1=128, C2=256, K=5, NC=2

typedef short bf16x8 __attribute__((ext_vector_type(8)));
typedef float f32x4 __attribute__((ext_vector_type(4)));

__device__ __forceinline__ ushort f2bf(float f) {
    uint u = __float_as_uint(f);
    u += 0x7fff + ((u >> 16) & 1);          // round-to-nearest-even
    return (ushort)(u >> 16);
}

// ---------------------------------------------------------------- embed
__global__ __launch_bounds__(256) void k_embed(const int* __restrict__ X, const float* __restrict__ sa,
                        const int* __restrict__ ptm, const float* __restrict__ emb,
                        const float* __restrict__ pemb, float* __restrict__ x0) {
    int idx = blockIdx.x * 256 + threadIdx.x;   // B*L*128 = 4194304
    int row = idx >> 7, e = idx & 127;
    float v;
    if (e < 120) v = emb[X[row] * 120 + e] * sa[row];
    else         v = pemb[ptm[row] * 8 + (e - 120)];
    x0[idx] = v;
}

// ---------------------------------------------------------------- QKV GEMM -> bf16 Q(scaled)/K/V
__global__ __launch_bounds__(256) void k_qkv(const float* __restrict__ x0, const float* __restrict__ W,
                      const float* __restrict__ bias, ushort* __restrict__ Qd,
                      ushort* __restrict__ Kd, ushort* __restrict__ Vd) {
    __shared__ float Ast[32][68];
    __shared__ float Bst[32][68];
    int m0 = blockIdx.y * 64, n0 = blockIdx.x * 64;
    int t = threadIdx.x, tx = t & 15, ty = t >> 4;
    float acc[4][4] = {};
    for (int kk = 0; kk < 128; kk += 32) {
        __syncthreads();
#pragma unroll
        for (int i = 0; i < 2; i++) {
            int idx = t + i * 256;
            int row = idx >> 3, c4 = (idx & 7) * 4;
            float4 a = *(const float4*)&x0[(m0 + row) * 128 + kk + c4];
            Ast[c4 + 0][row] = a.x; Ast[c4 + 1][row] = a.y;
            Ast[c4 + 2][row] = a.z; Ast[c4 + 3][row] = a.w;
            float4 b = *(const float4*)&W[(n0 + row) * 128 + kk + c4];
            Bst[c4 + 0][row] = b.x; Bst[c4 + 1][row] = b.y;
            Bst[c4 + 2][row] = b.z; Bst[c4 + 3][row] = b.w;
        }
        __syncthreads();
#pragma unroll
        for (int k2 = 0; k2 < 32; k2++) {
            float4 a4 = *(const float4*)&Ast[k2][ty * 4];
            float4 b4 = *(const float4*)&Bst[k2][tx * 4];
            acc[0][0] += a4.x * b4.x; acc[0][1] += a4.x * b4.y; acc[0][2] += a4.x * b4.z; acc[0][3] += a4.x * b4.w;
            acc[1][0] += a4.y * b4.x; acc[1][1] += a4.y * b4.y; acc[1][2] += a4.y * b4.z; acc[1][3] += a4.y * b4.w;
            acc[2][0] += a4.z * b4.x; acc[2][1] += a4.z * b4.y; acc[2][2] += a4.z * b4.z; acc[2][3] += a4.z * b4.w;
            acc[3][0] += a4.w * b4.x; acc[3][1] += a4.w * b4.y; acc[3][2] += a4.w * b4.z; acc[3][3] += a4.w * b4.w;
        }
    }
    int n = n0 + tx * 4;              // 4 consecutive cols, never straddles 32-boundary
    float4 bv = *(const float4*)&bias[n];
    int which = n >> 7, h = (n & 127) >> 5, hd = n & 31;
    ushort* dst = (which == 0) ? Qd : ((which == 1) ? Kd : Vd);
    float sc = (which == 0) ? 0.17677669529663687f : 1.0f;   // fold 1/sqrt(32) into Q
#pragma unroll
    for (int ii = 0; ii < 4; ii++) {
        int m = m0 + ty * 4 + ii;
        int bb = m >> 11, l = m & 2047;
        ushort4 o;
        o.x = f2bf((acc[ii][0] + bv.x) * sc); o.y = f2bf((acc[ii][1] + bv.y) * sc);
        o.z = f2bf((acc[ii][2] + bv.z) * sc); o.w = f2bf((acc[ii][3] + bv.w) * sc);
        *(ushort4*)&dst[(((size_t)(bb * 4 + h) * 2048) + l) * 32 + hd] = o;
    }
}

// ---------------------------------------------------------------- flash attention, bf16 MFMA
// A-frag layout: A[m=lane&15][k=quad*8+j]; B-frag: B[k=quad*8+j][n=lane&15];
// C/D: col=lane&15, row=quad*4+reg.  Scores tiny (inputs ~0.02 scale) -> exp without
// running max is exact softmax with huge overflow margin; l accumulates linearly.
__global__ __launch_bounds__(256) void k_attn2(const ushort* __restrict__ Qb, const ushort* __restrict__ Kb,
        const ushort* __restrict__ Vb, const float* __restrict__ rpe, float* __restrict__ AO) {
    __shared__ __attribute__((aligned(16))) ushort Kst[64][40];     // [key][hd], stride 80B (16B-mult)
    __shared__ __attribute__((aligned(16))) ushort Vt[32][72];      // [hd][key], stride 144B (16B-mult)
    __shared__ __attribute__((aligned(16))) ushort Pst[4][16][72];  // per-wave P, A-layout source
    __shared__ float sbias[66];
    int bh = blockIdx.y, h = bh & 3, bb = bh >> 2;
    int i0 = blockIdx.x * 64;
    int t = threadIdx.x, w = t >> 6, lane = t & 63;
    int lq = lane & 15, quad = lane >> 4;
    if (t < 65) sbias[t] = rpe[t * 4 + h];
    const ushort* Qp = Qb + ((size_t)bh * 2048 + i0 + w * 16) * 32;
    const ushort* Kp = Kb + (size_t)bh * 2048 * 32;
    const ushort* Vp = Vb + (size_t)bh * 2048 * 32;
    // Q fragment straight from global: lane pattern covers 1KB contiguous per wave
    bf16x8 qf = *(const bf16x8*)(Qp + lq * 32 + quad * 8);
    f32x4 o0 = {0.f, 0.f, 0.f, 0.f}, o1 = {0.f, 0.f, 0.f, 0.f};
    float lsum[4] = {0.f, 0.f, 0.f, 0.f};
    int iw = i0 + w * 16;
    int skey = t & 63, spart = t >> 6;     // staging assignment: key, hd-part

    for (int j0 = 0; j0 < 2048; j0 += 64) {
        __syncthreads();
        // stage K row-major
        uint4 kraw = *(const uint4*)(Kp + (size_t)(j0 + skey) * 32 + spart * 8);
        *(uint4*)&Kst[skey][spart * 8] = kraw;
        // stage V transposed (per-instr: all lanes same spart -> bank = key/2 -> 2-way = free)
        uint4 vraw = *(const uint4*)(Vp + (size_t)(j0 + skey) * 32 + spart * 8);
        const ushort* vsrc = (const ushort*)&vraw;
#pragma unroll
        for (int i2 = 0; i2 < 8; i2++) Vt[spart * 8 + i2][skey] = vsrc[i2];
        __syncthreads();
        // S = Q K^T : 4 key-tiles of 16
        f32x4 s[4];
#pragma unroll
        for (int tk = 0; tk < 4; tk++) {
            bf16x8 kf = *(const bf16x8*)&Kst[tk * 16 + lq][quad * 8];
            f32x4 z = {0.f, 0.f, 0.f, 0.f};
            s[tk] = __builtin_amdgcn_mfma_f32_16x16x32_bf16(qf, kf, z, 0, 0, 0);
        }
        // bias + exp + P->LDS (bf16) + l accumulation
        bool leftc  = (j0 + 63 - iw) <= -32;        // whole block clipped to d=-32
        bool rightc = (j0 - (iw + 15)) >= 32;       // whole block clipped to d=+32
        if (leftc | rightc) {
            float bconst = leftc ? sbias[0] : sbias[64];
#pragma unroll
            for (int tk = 0; tk < 4; tk++)
#pragma unroll
                for (int r = 0; r < 4; r++) {
                    float p = __expf(s[tk][r] + bconst);
                    lsum[r] += p;
                    Pst[w][quad * 4 + r][lq + 16 * tk] = f2bf(p);
                }
        } else {
#pragma unroll
            for (int tk = 0; tk < 4; tk++) {
                int j = j0 + tk * 16 + lq;
#pragma unroll
                for (int r = 0; r < 4; r++) {
                    int i = iw + quad * 4 + r;
                    int d = j - i; d = d < -32 ? -32 : (d > 32 ? 32 : d);
                    float p = __expf(s[tk][r] + sbias[d + 32]);
                    lsum[r] += p;
                    Pst[w][quad * 4 + r][lq + 16 * tk] = f2bf(p);
                }
            }
        }
        // O += P V  (per-wave Pst: same-wave lgkmcnt ordering, no barrier needed)
#pragma unroll
        for (int kh = 0; kh < 2; kh++) {
            bf16x8 pf  = *(const bf16x8*)&Pst[w][lq][kh * 32 + quad * 8];
            bf16x8 v0f = *(const bf16x8*)&Vt[lq][kh * 32 + quad * 8];
            bf16x8 v1f = *(const bf16x8*)&Vt[16 + lq][kh * 32 + quad * 8];
            o0 = __builtin_amdgcn_mfma_f32_16x16x32_bf16(pf, v0f, o0, 0, 0, 0);
            o1 = __builtin_amdgcn_mfma_f32_16x16x32_bf16(pf, v1f, o1, 0, 0, 0);
        }
    }
    // reduce l across the 16 lanes of each quad (rows quad*4+r)
#pragma unroll
    for (int r = 0; r < 4; r++) {
        float v = lsum[r];
#pragma unroll
        for (int off = 1; off < 16; off <<= 1) v += __shfl_xor(v, off);
        lsum[r] = v;
    }
#pragma unroll
    for (int r = 0; r < 4; r++) {
        float inv = 1.0f / lsum[r];
        int l = iw + quad * 4 + r;
        float* dst = &AO[((size_t)(bb * 2048 + l)) * 128 + h * 32];
        dst[lq]      = o0[r] * inv;
        dst[16 + lq] = o1[r] * inv;
    }
}

// ---------------------------------------------------------------- out-proj + residual + LN1
__global__ __launch_bounds__(256) void k_outproj_ln(const float* __restrict__ AO, const float* __restrict__ W,
        const float* __restrict__ bias, const float* __restrict__ x0,
        const float* __restrict__ g, const float* __restrict__ be, float* __restrict__ x1) {
    __shared__ float AOs[8][132];
    __shared__ float parts[4][4][2];
    int r0 = blockIdx.x * 8;
    int t = threadIdx.x;
    { int row = t >> 5, c4 = (t & 31) * 4;
      *(float4*)&AOs[row][c4] = *(const float4*)&AO[(size_t)(r0 + row) * 128 + c4]; }
    __syncthreads();
    int rg = t >> 7, d = t & 127;
    float acc[4] = {0.f, 0.f, 0.f, 0.f};
    const float4* W4 = (const float4*)(W + d * 128);
#pragma unroll
    for (int k4 = 0; k4 < 32; k4++) {
        float4 w = W4[k4];
#pragma unroll
        for (int rr = 0; rr < 4; rr++) {
            float4 a = *(const float4*)&AOs[rg * 4 + rr][k4 * 4];
            acc[rr] += w.x * a.x + w.y * a.y + w.z * a.z + w.w * a.w;
        }
    }
    float bd = bias[d];
    float vals[4];
#pragma unroll
    for (int rr = 0; rr < 4; rr++) {
        int row = r0 + rg * 4 + rr;
        vals[rr] = acc[rr] + bd + x0[(size_t)row * 128 + d];
    }
    int wv = t >> 6, lane = t & 63;
    float ssum[4], ssq[4];
#pragma unroll
    for (int rr = 0; rr < 4; rr++) {
        float a = vals[rr], b2 = vals[rr] * vals[rr];
#pragma unroll
        for (int off = 1; off < 64; off <<= 1) { a += __shfl_xor(a, off); b2 += __shfl_xor(b2, off); }
        ssum[rr] = a; ssq[rr] = b2;
    }
    if (lane == 0)
#pragma unroll
        for (int rr = 0; rr < 4; rr++) { parts[wv][rr][0] = ssum[rr]; parts[wv][rr][1] = ssq[rr]; }
    __syncthreads();
    int wo = wv ^ 1;
#pragma unroll
    for (int rr = 0; rr < 4; rr++) {
        float ts = parts[wv][rr][0] + parts[wo][rr][0];
        float tq = parts[wv][rr][1] + parts[wo][rr][1];
        float mean = ts * (1.0f / 128.0f);
        float var = tq * (1.0f / 128.0f) - mean * mean;
        float rs = rsqrtf(var + 1e-5f);
        int row = r0 + rg * 4 + rr;
        x1[(size_t)row * 128 + d] = (vals[rr] - mean) * rs * g[d] + be[d];
    }
}

// ---------------------------------------------------------------- FFN + residual + LN2
__global__ __launch_bounds__(256) void k_ffn_ln(const float* __restrict__ x1, const float* __restrict__ W1,
        const float* __restrict__ b1, const float* __restrict__ W2, const float* __restrict__ b2,
        const float* __restrict__ g, const float* __restrict__ be, float* __restrict__ x2) {
    __shared__ float xs[8][132];
    __shared__ float hst[8][260];
    __shared__ float parts[4][4][2];
    int r0 = blockIdx.x * 8;
    int t = threadIdx.x;
    { int row = t >> 5, c4 = (t & 31) * 4;
      *(float4*)&xs[row][c4] = *(const float4*)&x1[(size_t)(r0 + row) * 128 + c4]; }
    __syncthreads();
    float hacc[8] = {};
    const float4* W14 = (const float4*)(W1 + t * 128);
#pragma unroll
    for (int k4 = 0; k4 < 32; k4++) {
        float4 w = W14[k4];
#pragma unroll
        for (int r = 0; r < 8; r++) {
            float4 a = *(const float4*)&xs[r][k4 * 4];
            hacc[r] += w.x * a.x + w.y * a.y + w.z * a.z + w.w * a.w;
        }
    }
    float bb1 = b1[t];
#pragma unroll
    for (int r = 0; r < 8; r++) hst[r][t] = fmaxf(hacc[r] + bb1, 0.f);
    __syncthreads();
    int rg = t >> 7, d = t & 127;
    float acc[4] = {0.f, 0.f, 0.f, 0.f};
    const float4* W24 = (const float4*)(W2 + d * 256);
#pragma unroll
    for (int j4 = 0; j4 < 64; j4++) {
        float4 w = W24[j4];
#pragma unroll
        for (int rr = 0; rr < 4; rr++) {
            float4 hv = *(const float4*)&hst[rg * 4 + rr][j4 * 4];
            acc[rr] += w.x * hv.x + w.y * hv.y + w.z * hv.z + w.w * hv.w;
        }
    }
    float bd = b2[d];
    float vals[4];
#pragma unroll
    for (int rr = 0; rr < 4; rr++) vals[rr] = acc[rr] + bd + xs[rg * 4 + rr][d];
    int wv = t >> 6, lane = t & 63;
    float ssum[4], ssq[4];
#pragma unroll
    for (int rr = 0; rr < 4; rr++) {
        float a = vals[rr], q = vals[rr] * vals[rr];
#pragma unroll
        for (int off = 1; off < 64; off <<= 1) { a += __shfl_xor(a, off); q += __shfl_xor(q, off); }
        ssum[rr] = a; ssq[rr] = q;
    }
    if (lane == 0)
#pragma unroll
        for (int rr = 0; rr < 4; rr++) { parts[wv][rr][0] = ssum[rr]; parts[wv][rr][1] = ssq[rr]; }
    __syncthreads();
    int wo = wv ^ 1;
#pragma unroll
    for (int rr = 0; rr < 4; rr++) {
        float ts = parts[wv][rr][0] + parts[wo][rr][0];
        float tq = parts[wv][rr][1] + parts[wo][rr][1];
        float mean = ts * (1.0f / 128.0f);
        float var = tq * (1.0f / 128.0f) - mean * mean;
        float rs = rsqrtf(var + 1e-5f);
        int row = r0 + rg * 4 + rr;
        x2[(size_t)row * 128 + d] = (vals[rr] - mean) * rs * g[d] + be[d];
    }
}

// ---------------------------------------------------------------- conv (Cin=128 fixed), in [b][Lin][128], wt [ci][k][Cout], out [b][Lout][Cout]
__global__ __launch_bounds__(256) void k_conv(const float* __restrict__ in, const float* __restrict__ wt,
        const float* __restrict__ bias, float* __restrict__ out,
        int Lin, int Lout, int Cout, int pad) {
    __shared__ float s_in[68][132];
    __shared__ float s_w[5120];
    int b = blockIdx.z, lt = blockIdx.y, ct = blockIdx.x;
    int lbase = lt * 64, co0 = ct * 64;
    int t = threadIdx.x, tx = t & 15, ty = t >> 4;
#pragma unroll
    for (int i = 0; i < 9; i++) {
        int idx = t + i * 256;             // 2176 float4s
        if (idx < 2176) {
            int row = idx >> 5, c4 = (idx & 31) * 4;
            int gl = lbase - pad + row;
            float4 v = {0.f, 0.f, 0.f, 0.f};
            if (gl >= 0 && gl < Lin) v = *(const float4*)&in[((size_t)b * Lin + gl) * 128 + c4];
            *(float4*)&s_in[row][c4] = v;
        }
    }
    float acc[4][4] = {};
    for (int ci0 = 0; ci0 < 128; ci0 += 16) {
        __syncthreads();
#pragma unroll
        for (int i = 0; i < 5; i++) {
            int f4i = t + i * 256;          // 1280 float4s
            int flat = f4i * 4;
            int ci = flat / 320, rem = flat % 320;
            int kq = rem >> 6, co = rem & 63;
            *(float4*)&s_w[flat] = *(const float4*)&wt[((size_t)(ci0 + ci) * 5 + kq) * Cout + co0 + co];
        }
        __syncthreads();
#pragma unroll
        for (int ci = 0; ci < 16; ci++) {
            float a8[8];
#pragma unroll
            for (int x = 0; x < 8; x++) a8[x] = s_in[ty * 4 + x][ci0 + ci];
#pragma unroll
            for (int kq = 0; kq < 5; kq++) {
                float4 w = *(const float4*)&s_w[(ci * 5 + kq) * 64 + tx * 4];
#pragma unroll
                for (int il = 0; il < 4; il++) {
                    float a = a8[il + kq];
                    acc[il][0] += a * w.x; acc[il][1] += a * w.y;
                    acc[il][2] += a * w.z; acc[il][3] += a * w.w;
                }
            }
        }
    }
    float4 bv = *(const float4*)&bias[co0 + tx * 4];
#pragma unroll
    for (int il = 0; il < 4; il++) {
        int l = lbase + ty * 4 + il;
        if (l < Lout) {
            float4 o;
            o.x = acc[il][0] + bv.x; o.y = acc[il][1] + bv.y;
            o.z = acc[il][2] + bv.z; o.w = acc[il][3] + bv.w;
            *(float4*)&out[((size_t)b * Lout + l) * Cout + co0 + tx * 4] = o;
        }
    }
}

// ---------------------------------------------------------------- BN stats (two-stage, deterministic)
template <int C>
__global__ __launch_bounds__(256) void k_bnstats(const float* __restrict__ in, int rows, float* __restrict__ part) {
    __shared__ float buf[256][2];
    constexpr int RPI = 256 / C;
    int t = threadIdx.x;
    int c = t % C, rsub = t / C;
    float s = 0.f, s2 = 0.f;
    for (int r = blockIdx.x * RPI + rsub; r < rows; r += 256 * RPI) {
        float v = in[(size_t)r * C + c];
        s += v; s2 += v * v;
    }
    if (RPI > 1) {
        buf[t][0] = s; buf[t][1] = s2;
        __syncthreads();
        if (t < C) {
            s = buf[t][0] + buf[t + C][0];
            s2 = buf[t][1] + buf[t + C][1];
            part[(blockIdx.x * C + t) * 2] = s;
            part[(blockIdx.x * C + t) * 2 + 1] = s2;
        }
    } else {
        part[(blockIdx.x * C + c) * 2] = s;
        part[(blockIdx.x * C + c) * 2 + 1] = s2;
    }
}

__global__ void k_bnfin(const float* __restrict__ part, const float* __restrict__ g,
                        const float* __restrict__ be, float N, int C, float* __restrict__ ss) {
    int c = threadIdx.x;
    if (c >= C) return;
    float s = 0.f, s2 = 0.f;
    for (int pb = 0; pb < 256; pb++) {
        s += part[(pb * C + c) * 2];
        s2 += part[(pb * C + c) * 2 + 1];
    }
    float mean = s / N, var = s2 / N - mean * mean;
    float sc = g[c] * rsqrtf(var + 1e-5f);
    ss[c] = sc;
    ss[C + c] = be[c] - mean * sc;
}

// ---------------------------------------------------------------- BN1 + relu + maxpool(2)
__global__ __launch_bounds__(256) void k_bnrelu_pool(const float* __restrict__ c1, const float* __restrict__ ss,
                                                     float* __restrict__ p1) {
    int idx = blockIdx.x * 256 + threadIdx.x;    // 16*1024*128
    int c = idx & 127;
    int lp = (idx >> 7) & 1023;
    int b = idx >> 17;
    float sc = ss[c], sh = ss[128 + c];
    float v0 = c1[((size_t)b * 2048 + 2 * lp) * 128 + c];
    float v1 = c1[((size_t)b * 2048 + 2 * lp + 1) * 128 + c];
    float r0 = fmaxf(sc * v0 + sh, 0.f), r1 = fmaxf(sc * v1 + sh, 0.f);
    p1[idx] = fmaxf(r0, r1);
}

// ---------------------------------------------------------------- BN2 + relu + partial global max
__global__ __launch_bounds__(256) void k_pmax(const float* __restrict__ c2, const float* __restrict__ ss,
                                              float* __restrict__ pmax) {
    int ch = blockIdx.x, b = blockIdx.y;
    int c = threadIdx.x;
    float sc = ss[c], sh = ss[256 + c];
    float m = -1e30f;
    int lend = ch * 128 + 128; if (lend > 1020) lend = 1020;
    for (int l = ch * 128; l < lend; l++) {
        float v = c2[((size_t)b * 1020 + l) * 256 + c];
        m = fmaxf(m, sc * v + sh);
    }
    m = fmaxf(m, 0.f);     // relu(max) == max(relu)
    pmax[(b * 8 + ch) * 256 + c] = m;
}

// ---------------------------------------------------------------- final max + FC
__global__ __launch_bounds__(256) void k_fc(const float* __restrict__ pmax, const float* __restrict__ fcw,
                                            const float* __restrict__ fcb, float* __restrict__ outp) {
    __shared__ float red0[256], red1[256];
    int b = blockIdx.x, c = threadIdx.x;
    float m = 0.f;
#pragma unroll
    for (int ch = 0; ch < 8; ch++) m = fmaxf(m, pmax[(b * 8 + ch) * 256 + c]);
    red0[c] = fcw[c] * m;
    red1[c] = fcw[256 + c] * m;
    __syncthreads();
    for (int s = 128; s > 0; s >>= 1) {
        if (c < s) { red0[c] += red0[c + s]; red1[c] += red1[c + s]; }
        __syncthreads();
    }
    if (c == 0) { outp[b * 2] = red0[0] + fcb[0]; outp[b * 2 + 1] = red1[0] + fcb[1]; }
}

// ---------------------------------------------------------------- conv weight transpose [co][ci][k] -> [ci][k][co]
__global__ __launch_bounds__(256) void k_transw(const float* __restrict__ w1, const float* __restrict__ w2,
                                                float* __restrict__ wt1, float* __restrict__ wt2) {
    int idx = blockIdx.x * 256 + threadIdx.x;
    if (idx < 128 * 5 * 128) {
        int ci = idx / 640, rem = idx % 640, kq = rem >> 7, co = rem & 127;
        wt1[idx] = w1[(co * 128 + ci) * 5 + kq];
    }
    if (idx < 128 * 5 * 256) {
        int ci = idx / 1280, rem = idx % 1280, kq = rem >> 8, co = rem & 255;
        wt2[idx] = w2[(co * 128 + ci) * 5 + kq];
    }
}

// ---------------------------------------------------------------- launch
extern "C" void kernel_launch(void* const* d_in, const int* in_sizes, int n_in,
                              void* d_out, int out_size, void* d_ws, size_t ws_size,
                              hipStream_t stream) {
    const int*   X    = (const int*)d_in[0];
    const float* sa   = (const float*)d_in[1];
    const int*   ptm  = (const int*)d_in[2];
    const float* emb  = (const float*)d_in[3];
    const float* pemb = (const float*)d_in[4];
    const float* rpe  = (const float*)d_in[5];
    const float* ipw  = (const float*)d_in[6];
    const float* ipb  = (const float*)d_in[7];
    const float* opw  = (const float*)d_in[8];
    const float* opb  = (const float*)d_in[9];
    const float* l1w  = (const float*)d_in[10];
    const float* l1b  = (const float*)d_in[11];
    const float* l2w  = (const float*)d_in[12];
    const float* l2b  = (const float*)d_in[13];
    const float* ln1g = (const float*)d_in[14];
    const float* ln1b = (const float*)d_in[15];
    const float* ln2g = (const float*)d_in[16];
    const float* ln2b = (const float*)d_in[17];
    const float* c1w  = (const float*)d_in[18];
    const float* c1b  = (const float*)d_in[19];
    const float* bn1g = (const float*)d_in[20];
    const float* bn1b = (const float*)d_in[21];
    const float* c2w  = (const float*)d_in[22];
    const float* c2b  = (const float*)d_in[23];
    const float* bn2g = (const float*)d_in[24];
    const float* bn2b = (const float*)d_in[25];
    const float* fcw  = (const float*)d_in[26];
    const float* fcb  = (const float*)d_in[27];

    float* ws = (float*)d_ws;
    const size_t S = 4194304;          // one [16,2048,128] fp32 slot
    float*  x0 = ws;                   // slot0: x0, later c2
    ushort* Qd = (ushort*)(ws + S);    // slot1: Q bf16, later x1
    ushort* Kd = (ushort*)(ws + 2 * S);// slot2: K bf16, later x2
    ushort* Vd = (ushort*)(ws + 3 * S);// slot3: V bf16, later c1
    float*  AO = ws + 4 * S;           // slot4: AO, later p1
    float* x1  = ws + S;
    float* x2  = ws + 2 * S;
    float* c1  = ws + 3 * S;
    float* p1  = AO;
    float* c2  = x0;
    float* sm    = ws + 5 * S;
    float* wt1   = sm;                 // 81920
    float* wt2   = sm + 81920;         // 163840
    float* part1 = sm + 245760;        // 65536
    float* part2 = sm + 311296;        // 131072
    float* ss1   = sm + 442368;        // 256
    float* ss2   = sm + 442624;        // 512
    float* pmax  = sm + 443136;        // 32768

    k_transw<<<dim3(640), dim3(256), 0, stream>>>(c1w, c2w, wt1, wt2);
    k_embed<<<dim3(16384), dim3(256), 0, stream>>>(X, sa, ptm, emb, pemb, x0);
    k_qkv<<<dim3(6, 512), dim3(256), 0, stream>>>(x0, ipw, ipb, Qd, Kd, Vd);
    k_attn2<<<dim3(32, 64), dim3(256), 0, stream>>>(Qd, Kd, Vd, rpe, AO);
    k_outproj_ln<<<dim3(4096), dim3(256), 0, stream>>>(AO, opw, opb, x0, ln1g, ln1b, x1);
    k_ffn_ln<<<dim3(4096), dim3(256), 0, stream>>>(x1, l1w, l1b, l2w, l2b, ln2g, ln2b, x2);
    k_conv<<<dim3(2, 32, 16), dim3(256), 0, stream>>>(x2, wt1, c1b, c1, 2048, 2048, 128, 2);
    k_bnstats<128><<<dim3(256), dim3(256), 0, stream>>>(c1, 32768, part1);
    k_bnfin<<<dim3(1), dim3(128), 0, stream>>>(part1, bn1g, bn1b, 32768.0f, 128, ss1);
    k_bnrelu_pool<<<dim3(8192), dim3(256), 0, stream>>>(c1, ss1, p1);
    k_conv<<<dim3(4, 16, 16), dim3(256), 0, stream>>>(p1, wt2, c2b, c2, 1024, 1020, 256, 0);
    k_bnstats<256><<<dim3(256), dim3(256), 0, stream>>>(c2, 16320, part2);
    k_bnfin<<<dim3(1), dim3(256), 0, stream>>>(part2, bn2g, bn2b, 16320.0f, 256, ss2);
    k_pmax<<<dim3(8, 16), dim3(256), 0, stream>>>(c2, ss2, pmax);
    k_fc<<<dim3(16), dim3(256), 0, stream>>>(pmax, fcw, fcb, (float*)d_out);
}

// Round 3
// 501.312 us; speedup vs baseline: 2.9813x; 1.5966x over previous
//
#include <hip/hip_runtime.h>
#include <math.h>

// Problem constants
// B=16, L=2048, D=128, H=4, HD=32, FF=256, MD=32, C1=128, C2=256, K=5, NC=2

typedef short bf16x8 __attribute__((ext_vector_type(8)));
typedef float f32x4 __attribute__((ext_vector_type(4)));

__device__ __forceinline__ ushort f2bf(float f) {
    uint u = __float_as_uint(f);
    u += 0x7fff + ((u >> 16) & 1);          // round-to-nearest-even
    return (ushort)(u >> 16);
}

// ---------------------------------------------------------------- weight prep: fp32 -> bf16 (+ conv layout [k][co][ci])
__global__ __launch_bounds__(256) void k_prep(const float* __restrict__ ipw, const float* __restrict__ opw,
        const float* __restrict__ w1, const float* __restrict__ w2,
        const float* __restrict__ c1w, const float* __restrict__ c2w, ushort* __restrict__ wb) {
    int i = blockIdx.x * 256 + threadIdx.x;   // 376832 total
    float v;
    if (i < 49152) v = ipw[i];
    else if (i < 65536) v = opw[i - 49152];
    else if (i < 98304) v = w1[i - 65536];
    else if (i < 131072) v = w2[i - 98304];
    else if (i < 212992) {
        int j = i - 131072;                    // wtb1 [k][co][ci], co,ci 128
        int k = j / 16384, rem = j % 16384, co = rem >> 7, ci = rem & 127;
        v = c1w[(co * 128 + ci) * 5 + k];
    } else {
        int j = i - 212992;                    // wtb2 [k][co][ci], co 256, ci 128
        int k = j / 32768, rem = j % 32768, co = rem >> 7, ci = rem & 127;
        v = c2w[(co * 128 + ci) * 5 + k];
    }
    wb[i] = f2bf(v);
}

// ---------------------------------------------------------------- embed (fp32 + bf16)
__global__ __launch_bounds__(256) void k_embed(const int* __restrict__ X, const float* __restrict__ sa,
                        const int* __restrict__ ptm, const float* __restrict__ emb,
                        const float* __restrict__ pemb, float* __restrict__ x0, ushort* __restrict__ x0b) {
    int idx = blockIdx.x * 256 + threadIdx.x;   // B*L*128 = 4194304
    int row = idx >> 7, e = idx & 127;
    float v;
    if (e < 120) v = emb[X[row] * 120 + e] * sa[row];
    else         v = pemb[ptm[row] * 8 + (e - 120)];
    x0[idx] = v;
    x0b[idx] = f2bf(v);
}

// ---------------------------------------------------------------- QKV GEMM (MFMA) -> bf16 Q(scaled)/K/V
__global__ __launch_bounds__(256) void k_qkvm(const ushort* __restrict__ x0b, const ushort* __restrict__ ipwb,
        const float* __restrict__ bias, ushort* __restrict__ Qd, ushort* __restrict__ Kd, ushort* __restrict__ Vd) {
    int t = threadIdx.x, w = t >> 6, lane = t & 63;
    int lq = lane & 15, quad = lane >> 4;
    int r0 = blockIdx.x * 64;
    int bb = r0 >> 11, lw = (r0 & 2047) + w * 16;
    bf16x8 af[4];
#pragma unroll
    for (int ks = 0; ks < 4; ks++)
        af[ks] = *(const bf16x8*)&x0b[(size_t)(r0 + w * 16 + lq) * 128 + ks * 32 + quad * 8];
#pragma unroll
    for (int tn = 0; tn < 24; tn++) {
        f32x4 acc = {0.f, 0.f, 0.f, 0.f};
#pragma unroll
        for (int ks = 0; ks < 4; ks++) {
            bf16x8 bf = *(const bf16x8*)&ipwb[(size_t)(tn * 16 + lq) * 128 + ks * 32 + quad * 8];
            acc = __builtin_amdgcn_mfma_f32_16x16x32_bf16(af[ks], bf, acc, 0, 0, 0);
        }
        int n = tn * 16 + lq;
        float bv = bias[n];
        int which = tn >> 3;
        float sc = (which == 0) ? 0.17677669529663687f : 1.0f;
        ushort* dst = (which == 0) ? Qd : ((which == 1) ? Kd : Vd);
        int h = (tn & 7) >> 1, hd = (tn & 1) * 16 + lq;
#pragma unroll
        for (int r = 0; r < 4; r++) {
            int l = lw + quad * 4 + r;
            dst[((size_t)(bb * 4 + h) * 2048 + l) * 32 + hd] = f2bf((acc[r] + bv) * sc);
        }
    }
}

// ---------------------------------------------------------------- flash attention, bf16 MFMA (bf16 out)
__global__ __launch_bounds__(256) void k_attn2(const ushort* __restrict__ Qb, const ushort* __restrict__ Kb,
        const ushort* __restrict__ Vb, const float* __restrict__ rpe, ushort* __restrict__ AOb) {
    __shared__ __attribute__((aligned(16))) ushort Kst[64][40];     // [key][hd]
    __shared__ __attribute__((aligned(16))) ushort Vt[32][72];      // [hd][key]
    __shared__ __attribute__((aligned(16))) ushort Pst[4][16][72];  // per-wave P
    __shared__ float sbias[66];
    int bh = blockIdx.y, h = bh & 3, bb = bh >> 2;
    int i0 = blockIdx.x * 64;
    int t = threadIdx.x, w = t >> 6, lane = t & 63;
    int lq = lane & 15, quad = lane >> 4;
    if (t < 65) sbias[t] = rpe[t * 4 + h];
    const ushort* Qp = Qb + ((size_t)bh * 2048 + i0 + w * 16) * 32;
    const ushort* Kp = Kb + (size_t)bh * 2048 * 32;
    const ushort* Vp = Vb + (size_t)bh * 2048 * 32;
    bf16x8 qf = *(const bf16x8*)(Qp + lq * 32 + quad * 8);
    f32x4 o0 = {0.f, 0.f, 0.f, 0.f}, o1 = {0.f, 0.f, 0.f, 0.f};
    float lsum[4] = {0.f, 0.f, 0.f, 0.f};
    int iw = i0 + w * 16;
    int skey = t & 63, spart = t >> 6;

    for (int j0 = 0; j0 < 2048; j0 += 64) {
        __syncthreads();
        uint4 kraw = *(const uint4*)(Kp + (size_t)(j0 + skey) * 32 + spart * 8);
        *(uint4*)&Kst[skey][spart * 8] = kraw;
        uint4 vraw = *(const uint4*)(Vp + (size_t)(j0 + skey) * 32 + spart * 8);
        const ushort* vsrc = (const ushort*)&vraw;
#pragma unroll
        for (int i2 = 0; i2 < 8; i2++) Vt[spart * 8 + i2][skey] = vsrc[i2];
        __syncthreads();
        f32x4 s[4];
#pragma unroll
        for (int tk = 0; tk < 4; tk++) {
            bf16x8 kf = *(const bf16x8*)&Kst[tk * 16 + lq][quad * 8];
            f32x4 z = {0.f, 0.f, 0.f, 0.f};
            s[tk] = __builtin_amdgcn_mfma_f32_16x16x32_bf16(qf, kf, z, 0, 0, 0);
        }
        bool leftc  = (j0 + 63 - iw) <= -32;
        bool rightc = (j0 - (iw + 15)) >= 32;
        if (leftc | rightc) {
            float bconst = leftc ? sbias[0] : sbias[64];
#pragma unroll
            for (int tk = 0; tk < 4; tk++)
#pragma unroll
                for (int r = 0; r < 4; r++) {
                    float p = __expf(s[tk][r] + bconst);
                    lsum[r] += p;
                    Pst[w][quad * 4 + r][lq + 16 * tk] = f2bf(p);
                }
        } else {
#pragma unroll
            for (int tk = 0; tk < 4; tk++) {
                int j = j0 + tk * 16 + lq;
#pragma unroll
                for (int r = 0; r < 4; r++) {
                    int i = iw + quad * 4 + r;
                    int d = j - i; d = d < -32 ? -32 : (d > 32 ? 32 : d);
                    float p = __expf(s[tk][r] + sbias[d + 32]);
                    lsum[r] += p;
                    Pst[w][quad * 4 + r][lq + 16 * tk] = f2bf(p);
                }
            }
        }
#pragma unroll
        for (int kh = 0; kh < 2; kh++) {
            bf16x8 pf  = *(const bf16x8*)&Pst[w][lq][kh * 32 + quad * 8];
            bf16x8 v0f = *(const bf16x8*)&Vt[lq][kh * 32 + quad * 8];
            bf16x8 v1f = *(const bf16x8*)&Vt[16 + lq][kh * 32 + quad * 8];
            o0 = __builtin_amdgcn_mfma_f32_16x16x32_bf16(pf, v0f, o0, 0, 0, 0);
            o1 = __builtin_amdgcn_mfma_f32_16x16x32_bf16(pf, v1f, o1, 0, 0, 0);
        }
    }
#pragma unroll
    for (int r = 0; r < 4; r++) {
        float v = lsum[r];
#pragma unroll
        for (int off = 1; off < 16; off <<= 1) v += __shfl_xor(v, off);
        lsum[r] = v;
    }
#pragma unroll
    for (int r = 0; r < 4; r++) {
        float inv = 1.0f / lsum[r];
        int l = iw + quad * 4 + r;
        ushort* dst = &AOb[((size_t)(bb * 2048 + l)) * 128 + h * 32];
        dst[lq]      = f2bf(o0[r] * inv);
        dst[16 + lq] = f2bf(o1[r] * inv);
    }
}

// ---------------------------------------------------------------- out-proj (MFMA) + residual + LN1 -> x1 fp32 + bf16
__global__ __launch_bounds__(256) void k_oproj(const ushort* __restrict__ AOb, const ushort* __restrict__ opwb,
        const float* __restrict__ bias, const float* __restrict__ x0,
        const float* __restrict__ g, const float* __restrict__ be,
        float* __restrict__ x1, ushort* __restrict__ x1b) {
    int t = threadIdx.x, w = t >> 6, lane = t & 63;
    int lq = lane & 15, quad = lane >> 4;
    int r0 = blockIdx.x * 64;
    bf16x8 af[4];
#pragma unroll
    for (int ks = 0; ks < 4; ks++)
        af[ks] = *(const bf16x8*)&AOb[(size_t)(r0 + w * 16 + lq) * 128 + ks * 32 + quad * 8];
    f32x4 vals[8];
#pragma unroll
    for (int tn = 0; tn < 8; tn++) {
        f32x4 acc = {0.f, 0.f, 0.f, 0.f};
#pragma unroll
        for (int ks = 0; ks < 4; ks++) {
            bf16x8 bf = *(const bf16x8*)&opwb[(size_t)(tn * 16 + lq) * 128 + ks * 32 + quad * 8];
            acc = __builtin_amdgcn_mfma_f32_16x16x32_bf16(af[ks], bf, acc, 0, 0, 0);
        }
        int n = tn * 16 + lq;
        float bv = bias[n];
#pragma unroll
        for (int r = 0; r < 4; r++) {
            int row = r0 + w * 16 + quad * 4 + r;
            vals[tn][r] = acc[r] + bv + x0[(size_t)row * 128 + n];
        }
    }
    // per-row LN over 128 (cols live in 16 lanes of the quad x 8 tn regs)
#pragma unroll
    for (int r = 0; r < 4; r++) {
        float s = 0.f, q = 0.f;
#pragma unroll
        for (int tn = 0; tn < 8; tn++) { s += vals[tn][r]; q += vals[tn][r] * vals[tn][r]; }
#pragma unroll
        for (int off = 1; off < 16; off <<= 1) { s += __shfl_xor(s, off); q += __shfl_xor(q, off); }
        float mean = s * (1.0f / 128.0f);
        float var = q * (1.0f / 128.0f) - mean * mean;
        float rs = rsqrtf(var + 1e-5f);
        int row = r0 + w * 16 + quad * 4 + r;
#pragma unroll
        for (int tn = 0; tn < 8; tn++) {
            int n = tn * 16 + lq;
            float o = (vals[tn][r] - mean) * rs * g[n] + be[n];
            x1[(size_t)row * 128 + n] = o;
            x1b[(size_t)row * 128 + n] = f2bf(o);
        }
    }
}

// ---------------------------------------------------------------- FFN (MFMA) + residual + LN2 -> x2 bf16
__global__ __launch_bounds__(256) void k_ffnm(const ushort* __restrict__ x1b, const ushort* __restrict__ w1b,
        const float* __restrict__ b1, const ushort* __restrict__ w2b, const float* __restrict__ b2,
        const float* __restrict__ x1, const float* __restrict__ g, const float* __restrict__ be,
        ushort* __restrict__ x2b) {
    __shared__ __attribute__((aligned(16))) ushort hs[4][16][264];   // per-wave h (relu), A-layout source
    int t = threadIdx.x, w = t >> 6, lane = t & 63;
    int lq = lane & 15, quad = lane >> 4;
    int r0 = blockIdx.x * 64;
    bf16x8 af[4];
#pragma unroll
    for (int ks = 0; ks < 4; ks++)
        af[ks] = *(const bf16x8*)&x1b[(size_t)(r0 + w * 16 + lq) * 128 + ks * 32 + quad * 8];
    // GEMM1: h = relu(x1 @ W1^T + b1), 16 f-tiles
#pragma unroll
    for (int tf = 0; tf < 16; tf++) {
        f32x4 acc = {0.f, 0.f, 0.f, 0.f};
#pragma unroll
        for (int ks = 0; ks < 4; ks++) {
            bf16x8 bf = *(const bf16x8*)&w1b[(size_t)(tf * 16 + lq) * 128 + ks * 32 + quad * 8];
            acc = __builtin_amdgcn_mfma_f32_16x16x32_bf16(af[ks], bf, acc, 0, 0, 0);
        }
        float bv = b1[tf * 16 + lq];
#pragma unroll
        for (int r = 0; r < 4; r++)
            hs[w][quad * 4 + r][tf * 16 + lq] = f2bf(fmaxf(acc[r] + bv, 0.f));
    }
    // GEMM2: out = h @ W2^T + b2 + x1, LN2   (same-wave LDS: lgkmcnt ordering suffices)
    bf16x8 af2[8];
#pragma unroll
    for (int ks = 0; ks < 8; ks++)
        af2[ks] = *(const bf16x8*)&hs[w][lq][ks * 32 + quad * 8];
    f32x4 vals[8];
#pragma unroll
    for (int tn = 0; tn < 8; tn++) {
        f32x4 acc = {0.f, 0.f, 0.f, 0.f};
#pragma unroll
        for (int ks = 0; ks < 8; ks++) {
            bf16x8 bf = *(const bf16x8*)&w2b[(size_t)(tn * 16 + lq) * 256 + ks * 32 + quad * 8];
            acc = __builtin_amdgcn_mfma_f32_16x16x32_bf16(af2[ks], bf, acc, 0, 0, 0);
        }
        int n = tn * 16 + lq;
        float bv = b2[n];
#pragma unroll
        for (int r = 0; r < 4; r++) {
            int row = r0 + w * 16 + quad * 4 + r;
            vals[tn][r] = acc[r] + bv + x1[(size_t)row * 128 + n];
        }
    }
#pragma unroll
    for (int r = 0; r < 4; r++) {
        float s = 0.f, q = 0.f;
#pragma unroll
        for (int tn = 0; tn < 8; tn++) { s += vals[tn][r]; q += vals[tn][r] * vals[tn][r]; }
#pragma unroll
        for (int off = 1; off < 16; off <<= 1) { s += __shfl_xor(s, off); q += __shfl_xor(q, off); }
        float mean = s * (1.0f / 128.0f);
        float var = q * (1.0f / 128.0f) - mean * mean;
        float rs = rsqrtf(var + 1e-5f);
        int row = r0 + w * 16 + quad * 4 + r;
#pragma unroll
        for (int tn = 0; tn < 8; tn++) {
            int n = tn * 16 + lq;
            x2b[(size_t)row * 128 + n] = f2bf((vals[tn][r] - mean) * rs * g[n] + be[n]);
        }
    }
}

// ---------------------------------------------------------------- conv (MFMA): in bf16 [b][Lin][128], wt bf16 [k][Cout][128], out fp32 [b][Lout][Cout]
__global__ __launch_bounds__(256) void k_convm(const ushort* __restrict__ in, const ushort* __restrict__ wt,
        const float* __restrict__ bias, float* __restrict__ out,
        int Lin, int Lout, int Cout, int pad) {
    int t = threadIdx.x, w = t >> 6, lane = t & 63;
    int lq = lane & 15, quad = lane >> 4;
    int b = blockIdx.z, lt = blockIdx.y, ct = blockIdx.x;
    int l0 = lt * 64 + w * 16, co0 = ct * 128;
    f32x4 acc[8];
#pragma unroll
    for (int tn = 0; tn < 8; tn++) acc[tn] = (f32x4){0.f, 0.f, 0.f, 0.f};
    for (int k = 0; k < 5; k++) {
        int gl = l0 + lq + k - pad;
        bool valid = (gl >= 0) && (gl < Lin);
        bf16x8 af[4];
#pragma unroll
        for (int ks = 0; ks < 4; ks++) {
            bf16x8 z = {0, 0, 0, 0, 0, 0, 0, 0};
            af[ks] = valid ? *(const bf16x8*)&in[((size_t)b * Lin + gl) * 128 + ks * 32 + quad * 8] : z;
        }
#pragma unroll
        for (int tn = 0; tn < 8; tn++) {
#pragma unroll
            for (int ks = 0; ks < 4; ks++) {
                bf16x8 bf = *(const bf16x8*)&wt[((size_t)(k * Cout + co0 + tn * 16 + lq)) * 128 + ks * 32 + quad * 8];
                acc[tn] = __builtin_amdgcn_mfma_f32_16x16x32_bf16(af[ks], bf, acc[tn], 0, 0, 0);
            }
        }
    }
#pragma unroll
    for (int tn = 0; tn < 8; tn++) {
        int n = co0 + tn * 16 + lq;
        float bv = bias[n];
#pragma unroll
        for (int r = 0; r < 4; r++) {
            int l = l0 + quad * 4 + r;
            if (l < Lout) out[((size_t)b * Lout + l) * Cout + n] = acc[tn][r] + bv;
        }
    }
}

// ---------------------------------------------------------------- BN stats (two-stage, deterministic)
template <int C>
__global__ __launch_bounds__(256) void k_bnstats(const float* __restrict__ in, int rows, float* __restrict__ part) {
    __shared__ float buf[256][2];
    constexpr int RPI = 256 / C;
    int t = threadIdx.x;
    int c = t % C, rsub = t / C;
    float s = 0.f, s2 = 0.f;
    for (int r = blockIdx.x * RPI + rsub; r < rows; r += 256 * RPI) {
        float v = in[(size_t)r * C + c];
        s += v; s2 += v * v;
    }
    if (RPI > 1) {
        buf[t][0] = s; buf[t][1] = s2;
        __syncthreads();
        if (t < C) {
            s = buf[t][0] + buf[t + C][0];
            s2 = buf[t][1] + buf[t + C][1];
            part[(blockIdx.x * C + t) * 2] = s;
            part[(blockIdx.x * C + t) * 2 + 1] = s2;
        }
    } else {
        part[(blockIdx.x * C + c) * 2] = s;
        part[(blockIdx.x * C + c) * 2 + 1] = s2;
    }
}

__global__ void k_bnfin(const float* __restrict__ part, const float* __restrict__ g,
                        const float* __restrict__ be, float N, int C, float* __restrict__ ss) {
    int c = threadIdx.x;
    if (c >= C) return;
    float s = 0.f, s2 = 0.f;
    for (int pb = 0; pb < 256; pb++) {
        s += part[(pb * C + c) * 2];
        s2 += part[(pb * C + c) * 2 + 1];
    }
    float mean = s / N, var = s2 / N - mean * mean;
    float sc = g[c] * rsqrtf(var + 1e-5f);
    ss[c] = sc;
    ss[C + c] = be[c] - mean * sc;
}

// ---------------------------------------------------------------- BN1 + relu + maxpool(2) -> bf16
__global__ __launch_bounds__(256) void k_bnrelu_pool(const float* __restrict__ c1, const float* __restrict__ ss,
                                                     ushort* __restrict__ p1b) {
    int idx = blockIdx.x * 256 + threadIdx.x;    // 16*1024*128
    int c = idx & 127;
    int lp = (idx >> 7) & 1023;
    int b = idx >> 17;
    float sc = ss[c], sh = ss[128 + c];
    float v0 = c1[((size_t)b * 2048 + 2 * lp) * 128 + c];
    float v1 = c1[((size_t)b * 2048 + 2 * lp + 1) * 128 + c];
    float r0 = fmaxf(sc * v0 + sh, 0.f), r1 = fmaxf(sc * v1 + sh, 0.f);
    p1b[idx] = f2bf(fmaxf(r0, r1));
}

// ---------------------------------------------------------------- BN2 + relu + partial global max
__global__ __launch_bounds__(256) void k_pmax(const float* __restrict__ c2, const float* __restrict__ ss,
                                              float* __restrict__ pmax) {
    int ch = blockIdx.x, b = blockIdx.y;
    int c = threadIdx.x;
    float sc = ss[c], sh = ss[256 + c];
    float m = -1e30f;
    int lend = ch * 128 + 128; if (lend > 1020) lend = 1020;
    for (int l = ch * 128; l < lend; l++) {
        float v = c2[((size_t)b * 1020 + l) * 256 + c];
        m = fmaxf(m, sc * v + sh);
    }
    m = fmaxf(m, 0.f);
    pmax[(b * 8 + ch) * 256 + c] = m;
}

// ---------------------------------------------------------------- final max + FC
__global__ __launch_bounds__(256) void k_fc(const float* __restrict__ pmax, const float* __restrict__ fcw,
                                            const float* __restrict__ fcb, float* __restrict__ outp) {
    __shared__ float red0[256], red1[256];
    int b = blockIdx.x, c = threadIdx.x;
    float m = 0.f;
#pragma unroll
    for (int ch = 0; ch < 8; ch++) m = fmaxf(m, pmax[(b * 8 + ch) * 256 + c]);
    red0[c] = fcw[c] * m;
    red1[c] = fcw[256 + c] * m;
    __syncthreads();
    for (int s = 128; s > 0; s >>= 1) {
        if (c < s) { red0[c] += red0[c + s]; red1[c] += red1[c + s]; }
        __syncthreads();
    }
    if (c == 0) { outp[b * 2] = red0[0] + fcb[0]; outp[b * 2 + 1] = red1[0] + fcb[1]; }
}

// ---------------------------------------------------------------- launch
extern "C" void kernel_launch(void* const* d_in, const int* in_sizes, int n_in,
                              void* d_out, int out_size, void* d_ws, size_t ws_size,
                              hipStream_t stream) {
    const int*   X    = (const int*)d_in[0];
    const float* sa   = (const float*)d_in[1];
    const int*   ptm  = (const int*)d_in[2];
    const float* emb  = (const float*)d_in[3];
    const float* pemb = (const float*)d_in[4];
    const float* rpe  = (const float*)d_in[5];
    const float* ipw  = (const float*)d_in[6];
    const float* ipb  = (const float*)d_in[7];
    const float* opw  = (const float*)d_in[8];
    const float* opb  = (const float*)d_in[9];
    const float* l1w  = (const float*)d_in[10];
    const float* l1b  = (const float*)d_in[11];
    const float* l2w  = (const float*)d_in[12];
    const float* l2b  = (const float*)d_in[13];
    const float* ln1g = (const float*)d_in[14];
    const float* ln1b = (const float*)d_in[15];
    const float* ln2g = (const float*)d_in[16];
    const float* ln2b = (const float*)d_in[17];
    const float* c1w  = (const float*)d_in[18];
    const float* c1b  = (const float*)d_in[19];
    const float* bn1g = (const float*)d_in[20];
    const float* bn1b = (const float*)d_in[21];
    const float* c2w  = (const float*)d_in[22];
    const float* c2b  = (const float*)d_in[23];
    const float* bn2g = (const float*)d_in[24];
    const float* bn2b = (const float*)d_in[25];
    const float* fcw  = (const float*)d_in[26];
    const float* fcb  = (const float*)d_in[27];

    float* ws = (float*)d_ws;
    const size_t S = 4194304;               // one [16,2048,128] fp32 slot (floats)
    float*  x0  = ws;                       // slot0: x0 fp32, later c1 fp32
    float*  c1  = ws;
    float*  x1  = ws + S;                   // slot1: x1 fp32, later c2 fp32 (16320*256 <= S)
    float*  c2  = ws + S;
    ushort* Qd  = (ushort*)(ws + 2 * S);    // slot2: Q + K bf16
    ushort* Kd  = Qd + 4194304;
    ushort* Vd  = (ushort*)(ws + 3 * S);    // slot3: V + AO bf16
    ushort* AOb = Vd + 4194304;
    ushort* x0b = (ushort*)(ws + 4 * S);    // slot4: x0b (later x2b) + x1b
    ushort* x2b = x0b;
    ushort* x1b = x0b + 4194304;
    float*  sm  = ws + 5 * S;               // slot5: p1b + weights + stats
    ushort* p1b = (ushort*)sm;              // 2097152 bf16 = 1048576 floats
    float*  smw = sm + 1048576;
    ushort* wb  = (ushort*)smw;             // 376832 bf16 = 188416 floats
    ushort* ipwb = wb;                      // 49152
    ushort* opwb = wb + 49152;              // 16384
    ushort* w1b  = wb + 65536;              // 32768
    ushort* w2b  = wb + 98304;              // 32768
    ushort* wtb1 = wb + 131072;             // 81920
    ushort* wtb2 = wb + 212992;             // 163840
    float* part1 = smw + 188416;            // 65536
    float* part2 = part1 + 65536;           // 131072
    float* ss1   = part2 + 131072;          // 256
    float* ss2   = ss1 + 256;               // 512
    float* pmaxb = ss2 + 512;               // 32768

    k_prep<<<dim3(1472), dim3(256), 0, stream>>>(ipw, opw, l1w, l2w, c1w, c2w, wb);
    k_embed<<<dim3(16384), dim3(256), 0, stream>>>(X, sa, ptm, emb, pemb, x0, x0b);
    k_qkvm<<<dim3(512), dim3(256), 0, stream>>>(x0b, ipwb, ipb, Qd, Kd, Vd);
    k_attn2<<<dim3(32, 64), dim3(256), 0, stream>>>(Qd, Kd, Vd, rpe, AOb);
    k_oproj<<<dim3(512), dim3(256), 0, stream>>>(AOb, opwb, opb, x0, ln1g, ln1b, x1, x1b);
    k_ffnm<<<dim3(512), dim3(256), 0, stream>>>(x1b, w1b, l1b, w2b, l2b, x1, ln2g, ln2b, x2b);
    k_convm<<<dim3(1, 32, 16), dim3(256), 0, stream>>>(x2b, wtb1, c1b, c1, 2048, 2048, 128, 2);
    k_bnstats<128><<<dim3(256), dim3(256), 0, stream>>>(c1, 32768, part1);
    k_bnfin<<<dim3(1), dim3(128), 0, stream>>>(part1, bn1g, bn1b, 32768.0f, 128, ss1);
    k_bnrelu_pool<<<dim3(8192), dim3(256), 0, stream>>>(c1, ss1, p1b);
    k_convm<<<dim3(2, 16, 16), dim3(256), 0, stream>>>(p1b, wtb2, c2b, c2, 1024, 1020, 256, 0);
    k_bnstats<256><<<dim3(256), dim3(256), 0, stream>>>(c2, 16320, part2);
    k_bnfin<<<dim3(1), dim3(256), 0, stream>>>(part2, bn2g, bn2b, 16320.0f, 256, ss2);
    k_pmax<<<dim3(8, 16), dim3(256), 0, stream>>>(c2, ss2, pmaxb);
    k_fc<<<dim3(16), dim3(256), 0, stream>>>(pmaxb, fcw, fcb, (float*)d_out);
}